// Round 7
// baseline (162.268 us; speedup 1.0000x reference)
//
#include <hip/hip_runtime.h>
#include <hip/hip_bf16.h>
#include <stdint.h>

// out[b,n,o] = sum_t x[b,n,t] * (sum_g y[b,g]*w[g,o,t]*mask[o,t]) + bias[o]
// B=32 N=256 T=1024 O=1024 G=8.  bf16 MFMA path (absmax 0.031 vs thr 0.154).
//
//  K1 prep: mix blocks (4096): 64 lanes/wave own one (o, 4t) footprint; the
//           4 waves of a block each handle 8 of the 32 b's (wave-level b-split:
//           R4's parallelism without R4's +96MB HBM re-fetch -- waves 2..4 hit
//           L1 on the shared w tile).  b-phase stagger kept.
//           cvt blocks (1024): xb=bf16(x).
//  K2 gemm: (R4..R6 byte-identical) 128x128 tile, BK=64, 512 thr / 8 waves,
//           XOR-swizzled LDS, double-buffered global_load_lds.

#define B_ 32
#define N_ 256
#define T_ 1024
#define O_ 1024
#define G_ 8

#define BM 128
#define BN 128
#define BK 64            // elems; LDS row = 128 B = 8 x 16 B chunks
#define BUFSZ (BM * BK)  // 8192 elems = 16 KiB

typedef __attribute__((__ext_vector_type__(8))) __bf16 bf16x8;
typedef __attribute__((__ext_vector_type__(4))) float  f32x4;

__device__ __forceinline__ unsigned short f2bf(float f) {
    union { float f; uint32_t u; } v; v.f = f;
    uint32_t u = v.u;
    uint32_t r = (u + 0x7fffu + ((u >> 16) & 1u)) >> 16;  // RNE
    return (unsigned short)r;
}

__device__ __forceinline__ uint4 pack8(const float* a) {
    uint4 r;
    r.x = (uint32_t)f2bf(a[0]) | ((uint32_t)f2bf(a[1]) << 16);
    r.y = (uint32_t)f2bf(a[2]) | ((uint32_t)f2bf(a[3]) << 16);
    r.z = (uint32_t)f2bf(a[4]) | ((uint32_t)f2bf(a[5]) << 16);
    r.w = (uint32_t)f2bf(a[6]) | ((uint32_t)f2bf(a[7]) << 16);
    return r;
}

#define MIXB 4096   // O*T/4 lanes / 64 ; each block = one 64-lane footprint x 4 waves(b)
#define CVTB 1024   // 262144 threads, 8 float4 each

// --- K1: fused prologue.
__global__ __launch_bounds__(256) void prep_kernel(
    const float* __restrict__ w,     // [G,O,T]
    const float* __restrict__ mask,  // [O,T]
    const float* __restrict__ y,     // [B,G]
    const float* __restrict__ x,     // [B,N,T]
    unsigned short* __restrict__ Wb, // [B,O,T] bf16
    unsigned short* __restrict__ xb) // [B,N,T] bf16
{
    const int tid = threadIdx.x;
    if (blockIdx.x < MIXB) {
        const int lane = tid & 63;
        const int wv_  = tid >> 6;                 // wave 0..3 -> b group
        const int idx  = blockIdx.x * 64 + lane;   // over O*T/4
        const int o    = idx >> 8;                 // 256 four-elem groups per o
        const int t    = (idx & 255) << 2;

        const float4 m4 = *(const float4*)(mask + (size_t)o * T_ + t);

        float wvv[G_][4];   // masked w; identical across the 4 waves -> L1 hits
#pragma unroll
        for (int g = 0; g < G_; ++g) {
            const float4 a = *(const float4*)(w + ((size_t)g * O_ + o) * T_ + t);
            wvv[g][0] = a.x * m4.x; wvv[g][1] = a.y * m4.y;
            wvv[g][2] = a.z * m4.z; wvv[g][3] = a.w * m4.w;
        }
        unsigned short* dst = Wb + (size_t)o * T_ + t;
        const int bg  = wv_ * 8;
        const int bph = blockIdx.x & 7;            // phase stagger within b-slice
#pragma unroll
        for (int bi = 0; bi < 8; ++bi) {
            const int b = bg + ((bi + bph) & 7);   // wave-uniform
            const float4 y0 = *(const float4*)(y + b * G_);
            const float4 y1 = *(const float4*)(y + b * G_ + 4);
            const float yv[G_] = {y0.x, y0.y, y0.z, y0.w, y1.x, y1.y, y1.z, y1.w};
            float acc[4] = {};
#pragma unroll
            for (int g = 0; g < G_; ++g)
#pragma unroll
                for (int j = 0; j < 4; ++j)
                    acc[j] += yv[g] * wvv[g][j];
            ushort4 pk;
            pk.x = f2bf(acc[0]); pk.y = f2bf(acc[1]);
            pk.z = f2bf(acc[2]); pk.w = f2bf(acc[3]);
            *(ushort4*)(dst + (size_t)b * O_ * T_) = pk;
        }
    } else {
        // cvt: 8 float4 per thread (2 consecutive per step, 4 strided steps)
        const int i = (blockIdx.x - MIXB) * 256 + tid;
        const float4* x4 = (const float4*)x;
        uint4* o4 = (uint4*)xb;
#pragma unroll
        for (int j = 0; j < 4; ++j) {
            const size_t f4 = (size_t)j * 524288 + (size_t)i * 2;
            const float4 a = x4[f4];
            const float4 b = x4[f4 + 1];
            const float v[8] = {a.x, a.y, a.z, a.w, b.x, b.y, b.z, b.w};
            o4[(size_t)j * 262144 + i] = pack8(v);
        }
    }
}

__device__ __forceinline__ void load16_to_lds(const unsigned short* g, unsigned short* l) {
    __builtin_amdgcn_global_load_lds(
        (const __attribute__((address_space(1))) unsigned char*)g,
        (__attribute__((address_space(3))) unsigned char*)l,
        16, 0, 0);
}

// --- K2: batched GEMM, C = A . B^T, K-major bf16 both sides. (unchanged)
// 512 threads = 8 waves (2m x 4n), wave tile 64x32, acc 4x2.
// LDS chunk c of row r holds global chunk (c ^ (r&7)); ds_read_b128 phases
// spread over all 8 bank-groups (2 lanes each = free, m136).
__global__ __launch_bounds__(512, 4) void gemm_kernel(
    const unsigned short* __restrict__ xb,   // [B][N_][T_] bf16
    const unsigned short* __restrict__ Wb,   // [B][O_][T_] bf16
    const float* __restrict__ bias,          // [O_]
    float* __restrict__ out)                 // [B][N_][O_] f32
{
    __shared__ __align__(16) unsigned short lA[2 * BUFSZ];  // 32 KiB
    __shared__ __align__(16) unsigned short lB[2 * BUFSZ];  // 32 KiB

    const int tn = blockIdx.x;   // 0..7  (o tiles)
    const int tm = blockIdx.y;   // 0..1  (n tiles)
    const int b  = blockIdx.z;   // 0..31

    const int tid  = threadIdx.x;
    const int lane = tid & 63;
    const int wave = tid >> 6;          // 0..7
    const int wm   = (wave >> 2) * 64;  // 2 in m
    const int wn   = (wave & 3) * 32;   // 4 in n

    const unsigned short* Ab = xb + (size_t)b * N_ * T_ + (size_t)(tm * BM) * T_;
    const unsigned short* Bb = Wb + (size_t)b * O_ * T_ + (size_t)(tn * BN) * T_;

    // staging: round r: LDS elem tid*8 + r*4096 -> row tid/8 + r*64, chunk tid&7
    const int srow   = tid >> 3;                 // 0..63
    const int schunk = (tid & 7) ^ (srow & 7);
    const unsigned short* ga0 = Ab + (size_t)srow * T_ + schunk * 8;
    const unsigned short* gb0 = Bb + (size_t)srow * T_ + schunk * 8;

#define STAGE(buf, kt)                                                          \
    {                                                                           \
        unsigned short* lad = lA + (buf) * BUFSZ + tid * 8;                     \
        unsigned short* lbd = lB + (buf) * BUFSZ + tid * 8;                     \
        _Pragma("unroll")                                                       \
        for (int r_ = 0; r_ < 2; ++r_) {                                        \
            load16_to_lds(ga0 + (kt) + (size_t)(r_ * 64) * T_, lad + r_ * 4096);\
            load16_to_lds(gb0 + (kt) + (size_t)(r_ * 64) * T_, lbd + r_ * 4096);\
        }                                                                       \
    }

    f32x4 acc[4][2] = {};

    const int fr = lane & 15;       // fragment row within 16
    const int q  = lane >> 4;       // k-quad 0..3
    const int sw = fr & 7;          // row&7 (wm/wn and i*16 are multiples of 8)

#define COMPUTE(buf)                                                            \
    {                                                                           \
        const unsigned short* la = lA + (buf) * BUFSZ;                          \
        const unsigned short* lb = lB + (buf) * BUFSZ;                          \
        _Pragma("unroll")                                                       \
        for (int kk = 0; kk < 2; ++kk) {                                        \
            const int cp = ((kk * 4 + q) ^ sw) * 8;                             \
            bf16x8 afr[4], bfr[2];                                              \
            _Pragma("unroll")                                                   \
            for (int i_ = 0; i_ < 4; ++i_)                                      \
                afr[i_] = *(const bf16x8*)(la + (wm + i_ * 16 + fr) * BK + cp); \
            _Pragma("unroll")                                                   \
            for (int i_ = 0; i_ < 2; ++i_)                                      \
                bfr[i_] = *(const bf16x8*)(lb + (wn + i_ * 16 + fr) * BK + cp); \
            _Pragma("unroll")                                                   \
            for (int mi = 0; mi < 4; ++mi)                                      \
                _Pragma("unroll")                                               \
                for (int ni = 0; ni < 2; ++ni)                                  \
                    acc[mi][ni] = __builtin_amdgcn_mfma_f32_16x16x32_bf16(      \
                        afr[mi], bfr[ni], acc[mi][ni], 0, 0, 0);                \
        }                                                                       \
    }

    STAGE(0, 0)
    for (int kt = 0; kt < T_; kt += 2 * BK) {
        __syncthreads();                       // buf0(kt) staged
        STAGE(1, kt + BK)                      // prefetch buf1
        COMPUTE(0)
        __syncthreads();                       // buf1 staged; buf0 reads done
        if (kt + 2 * BK < T_) STAGE(0, kt + 2 * BK)
        COMPUTE(1)
    }

    // Epilogue: D[row=(lane>>4)*4+r][col=lane&15] (m89/m91) + bias.
    float* outb = out + (size_t)b * N_ * O_ + (size_t)(tm * BM) * O_ + (tn * BN);
    const int cn = lane & 15;
    const int cr = (lane >> 4) * 4;
#pragma unroll
    for (int ni = 0; ni < 2; ++ni) {
        const int col = wn + ni * 16 + cn;
        const float bv = bias[tn * BN + col];
#pragma unroll
        for (int mi = 0; mi < 4; ++mi) {
#pragma unroll
            for (int r = 0; r < 4; ++r) {
                const int row = wm + mi * 16 + cr + r;
                outb[(size_t)row * O_ + col] = acc[mi][ni][r] + bv;
            }
        }
    }
}

// --- Fallback (ws too small): correct fp32 path.
__global__ __launch_bounds__(256) void naive_kernel(
    const float* __restrict__ x, const float* __restrict__ y,
    const float* __restrict__ w, const float* __restrict__ mask,
    const float* __restrict__ bias, float* __restrict__ out)
{
    const int oc = blockIdx.x & 3;
    const int n  = (blockIdx.x >> 2) & (N_ - 1);
    const int b  = blockIdx.x >> 10;

    __shared__ float xs[T_];
    __shared__ float ys[G_];
    const float* xrow = x + ((size_t)b * N_ + n) * T_;
    for (int i = threadIdx.x; i < T_ / 4; i += 256)
        ((float4*)xs)[i] = ((const float4*)xrow)[i];
    if (threadIdx.x < G_) ys[threadIdx.x] = y[b * G_ + threadIdx.x];
    __syncthreads();

    const int o = oc * 256 + threadIdx.x;
    float acc = 0.f;
    for (int t = 0; t < T_; t += 4) {
        const float4 m4 = *(const float4*)(mask + (size_t)o * T_ + t);
        float4 s = {0.f, 0.f, 0.f, 0.f};
#pragma unroll
        for (int g = 0; g < G_; ++g) {
            const float4 w4 = *(const float4*)(w + ((size_t)g * O_ + o) * T_ + t);
            const float yv = ys[g];
            s.x += yv * w4.x; s.y += yv * w4.y; s.z += yv * w4.z; s.w += yv * w4.w;
        }
        acc += xs[t] * m4.x * s.x + xs[t + 1] * m4.y * s.y
             + xs[t + 2] * m4.z * s.z + xs[t + 3] * m4.w * s.w;
    }
    out[((size_t)b * N_ + n) * O_ + o] = acc + bias[o];
}

extern "C" void kernel_launch(void* const* d_in, const int* in_sizes, int n_in,
                              void* d_out, int out_size, void* d_ws, size_t ws_size,
                              hipStream_t stream) {
    const float* x    = (const float*)d_in[0];
    const float* y    = (const float*)d_in[1];
    const float* w    = (const float*)d_in[2];
    const float* mask = (const float*)d_in[3];
    const float* bias = (const float*)d_in[4];
    float* out = (float*)d_out;

    const size_t wb_bytes = (size_t)B_ * O_ * T_ * sizeof(unsigned short); // 64 MiB
    const size_t xb_bytes = (size_t)B_ * N_ * T_ * sizeof(unsigned short); // 16 MiB

    if (ws_size >= wb_bytes + xb_bytes) {
        unsigned short* Wb = (unsigned short*)d_ws;
        unsigned short* xb = (unsigned short*)((char*)d_ws + wb_bytes);
        prep_kernel<<<MIXB + CVTB, 256, 0, stream>>>(w, mask, y, x, Wb, xb);
        dim3 grid(O_ / BN, N_ / BM, B_);
        gemm_kernel<<<grid, 512, 0, stream>>>(xb, Wb, bias, out);
    } else {
        naive_kernel<<<B_ * N_ * (O_ / 256), 256, 0, stream>>>(x, y, w, mask, bias, out);
    }
}

// Round 8
// 159.428 us; speedup vs baseline: 1.0178x; 1.0178x over previous
//
#include <hip/hip_runtime.h>
#include <hip/hip_bf16.h>
#include <stdint.h>

// out[b,n,o] = sum_t x[b,n,t] * (sum_g y[b,g]*w[g,o,t]*mask[o,t]) + bias[o]
// B=32 N=256 T=1024 O=1024 G=8.  bf16 MFMA path (absmax 0.031 vs thr 0.154).
//
//  Wb layout: b-slice stride = O*T + 2048 elems (+4 KB pad). Unpadded 2 MiB
//  stride aliased every thread's 32 b-strided stores into ONE L2 set
//  (4 MiB/16-way/XCD -> set bits < 2 MiB) => eviction storm, ~2 TB/s writes.
//  +4 KB puts consecutive b-slices 32 sets apart. (R4's 8-slice split fit
//  16 ways and hit 3.1 TB/s -- the one fast variant, explained.)
//
//  K1 prep: mix blocks (1024): thread owns 4 t of one o, loops 32 b staggered.
//           cvt blocks (1024): xb=bf16(x).   (R6 config, best: 43.4 us)
//  K2 gemm: (R4..R7 structure) 128x128 tile, BK=64, 512 thr / 8 waves,
//           XOR-swizzled LDS, double-buffered global_load_lds.

#define B_ 32
#define N_ 256
#define T_ 1024
#define O_ 1024
#define G_ 8

#define WSTRIDE ((size_t)(O_ * T_ + 2048))   // padded b-slice stride, elems

#define BM 128
#define BN 128
#define BK 64            // elems; LDS row = 128 B = 8 x 16 B chunks
#define BUFSZ (BM * BK)  // 8192 elems = 16 KiB

typedef __attribute__((__ext_vector_type__(8))) __bf16 bf16x8;
typedef __attribute__((__ext_vector_type__(4))) float  f32x4;

__device__ __forceinline__ unsigned short f2bf(float f) {
    union { float f; uint32_t u; } v; v.f = f;
    uint32_t u = v.u;
    uint32_t r = (u + 0x7fffu + ((u >> 16) & 1u)) >> 16;  // RNE
    return (unsigned short)r;
}

__device__ __forceinline__ uint4 pack8(const float* a) {
    uint4 r;
    r.x = (uint32_t)f2bf(a[0]) | ((uint32_t)f2bf(a[1]) << 16);
    r.y = (uint32_t)f2bf(a[2]) | ((uint32_t)f2bf(a[3]) << 16);
    r.z = (uint32_t)f2bf(a[4]) | ((uint32_t)f2bf(a[5]) << 16);
    r.w = (uint32_t)f2bf(a[6]) | ((uint32_t)f2bf(a[7]) << 16);
    return r;
}

#define MIXB 1024   // O*T/4 threads / 256
#define CVTB 1024   // 262144 threads, 8 float4 each

// --- K1: fused prologue.
__global__ __launch_bounds__(256) void prep_kernel(
    const float* __restrict__ w,     // [G,O,T]
    const float* __restrict__ mask,  // [O,T]
    const float* __restrict__ y,     // [B,G]
    const float* __restrict__ x,     // [B,N,T]
    unsigned short* __restrict__ Wb, // [B][WSTRIDE] bf16 (padded)
    unsigned short* __restrict__ xb) // [B,N,T] bf16
{
    const int tid = threadIdx.x;
    if (blockIdx.x < MIXB) {
        const int idx = blockIdx.x * 256 + tid;   // over O*T/4
        const int o   = idx >> 8;                 // 256 four-elem groups per o
        const int t   = (idx & 255) << 2;

        const float4 m4 = *(const float4*)(mask + (size_t)o * T_ + t);

        float wv[G_][4];
#pragma unroll
        for (int g = 0; g < G_; ++g) {
            const float4 a = *(const float4*)(w + ((size_t)g * O_ + o) * T_ + t);
            wv[g][0] = a.x * m4.x; wv[g][1] = a.y * m4.y;
            wv[g][2] = a.z * m4.z; wv[g][3] = a.w * m4.w;
        }
        unsigned short* dst = Wb + (size_t)o * T_ + t;
        const int bph = blockIdx.x & (B_ - 1);    // per-block b phase stagger
#pragma unroll 4
        for (int bi = 0; bi < B_; ++bi) {
            const int b = (bi + bph) & (B_ - 1);  // block-uniform -> scalar y loads
            const float4 y0 = *(const float4*)(y + b * G_);
            const float4 y1 = *(const float4*)(y + b * G_ + 4);
            const float yv[G_] = {y0.x, y0.y, y0.z, y0.w, y1.x, y1.y, y1.z, y1.w};
            float acc[4] = {};
#pragma unroll
            for (int g = 0; g < G_; ++g)
#pragma unroll
                for (int j = 0; j < 4; ++j)
                    acc[j] += yv[g] * wv[g][j];
            ushort4 pk;
            pk.x = f2bf(acc[0]); pk.y = f2bf(acc[1]);
            pk.z = f2bf(acc[2]); pk.w = f2bf(acc[3]);
            *(ushort4*)(dst + (size_t)b * WSTRIDE) = pk;
        }
    } else {
        // cvt: 8 float4 per thread (2 consecutive per step, 4 strided steps)
        const int i = (blockIdx.x - MIXB) * 256 + tid;
        const float4* x4 = (const float4*)x;
        uint4* o4 = (uint4*)xb;
#pragma unroll
        for (int j = 0; j < 4; ++j) {
            const size_t f4 = (size_t)j * 524288 + (size_t)i * 2;
            const float4 a = x4[f4];
            const float4 b = x4[f4 + 1];
            const float v[8] = {a.x, a.y, a.z, a.w, b.x, b.y, b.z, b.w};
            o4[(size_t)j * 262144 + i] = pack8(v);
        }
    }
}

__device__ __forceinline__ void load16_to_lds(const unsigned short* g, unsigned short* l) {
    __builtin_amdgcn_global_load_lds(
        (const __attribute__((address_space(1))) unsigned char*)g,
        (__attribute__((address_space(3))) unsigned char*)l,
        16, 0, 0);
}

// --- K2: batched GEMM, C = A . B^T, K-major bf16 both sides.
// 512 threads = 8 waves (2m x 4n), wave tile 64x32, acc 4x2.
// LDS chunk c of row r holds global chunk (c ^ (r&7)); ds_read_b128 phases
// spread over all 8 bank-groups (2 lanes each = free, m136).
__global__ __launch_bounds__(512, 4) void gemm_kernel(
    const unsigned short* __restrict__ xb,   // [B][N_][T_] bf16
    const unsigned short* __restrict__ Wb,   // [B][WSTRIDE] bf16 (padded)
    const float* __restrict__ bias,          // [O_]
    float* __restrict__ out)                 // [B][N_][O_] f32
{
    __shared__ __align__(16) unsigned short lA[2 * BUFSZ];  // 32 KiB
    __shared__ __align__(16) unsigned short lB[2 * BUFSZ];  // 32 KiB

    const int tn = blockIdx.x;   // 0..7  (o tiles)
    const int tm = blockIdx.y;   // 0..1  (n tiles)
    const int b  = blockIdx.z;   // 0..31

    const int tid  = threadIdx.x;
    const int lane = tid & 63;
    const int wave = tid >> 6;          // 0..7
    const int wm   = (wave >> 2) * 64;  // 2 in m
    const int wn   = (wave & 3) * 32;   // 4 in n

    const unsigned short* Ab = xb + (size_t)b * N_ * T_ + (size_t)(tm * BM) * T_;
    const unsigned short* Bb = Wb + (size_t)b * WSTRIDE + (size_t)(tn * BN) * T_;

    // staging: round r: LDS elem tid*8 + r*4096 -> row tid/8 + r*64, chunk tid&7
    const int srow   = tid >> 3;                 // 0..63
    const int schunk = (tid & 7) ^ (srow & 7);
    const unsigned short* ga0 = Ab + (size_t)srow * T_ + schunk * 8;
    const unsigned short* gb0 = Bb + (size_t)srow * T_ + schunk * 8;

#define STAGE(buf, kt)                                                          \
    {                                                                           \
        unsigned short* lad = lA + (buf) * BUFSZ + tid * 8;                     \
        unsigned short* lbd = lB + (buf) * BUFSZ + tid * 8;                     \
        _Pragma("unroll")                                                       \
        for (int r_ = 0; r_ < 2; ++r_) {                                        \
            load16_to_lds(ga0 + (kt) + (size_t)(r_ * 64) * T_, lad + r_ * 4096);\
            load16_to_lds(gb0 + (kt) + (size_t)(r_ * 64) * T_, lbd + r_ * 4096);\
        }                                                                       \
    }

    f32x4 acc[4][2] = {};

    const int fr = lane & 15;       // fragment row within 16
    const int q  = lane >> 4;       // k-quad 0..3
    const int sw = fr & 7;          // row&7 (wm/wn and i*16 are multiples of 8)

#define COMPUTE(buf)                                                            \
    {                                                                           \
        const unsigned short* la = lA + (buf) * BUFSZ;                          \
        const unsigned short* lb = lB + (buf) * BUFSZ;                          \
        _Pragma("unroll")                                                       \
        for (int kk = 0; kk < 2; ++kk) {                                        \
            const int cp = ((kk * 4 + q) ^ sw) * 8;                             \
            bf16x8 afr[4], bfr[2];                                              \
            _Pragma("unroll")                                                   \
            for (int i_ = 0; i_ < 4; ++i_)                                      \
                afr[i_] = *(const bf16x8*)(la + (wm + i_ * 16 + fr) * BK + cp); \
            _Pragma("unroll")                                                   \
            for (int i_ = 0; i_ < 2; ++i_)                                      \
                bfr[i_] = *(const bf16x8*)(lb + (wn + i_ * 16 + fr) * BK + cp); \
            _Pragma("unroll")                                                   \
            for (int mi = 0; mi < 4; ++mi)                                      \
                _Pragma("unroll")                                               \
                for (int ni = 0; ni < 2; ++ni)                                  \
                    acc[mi][ni] = __builtin_amdgcn_mfma_f32_16x16x32_bf16(      \
                        afr[mi], bfr[ni], acc[mi][ni], 0, 0, 0);                \
        }                                                                       \
    }

    STAGE(0, 0)
    for (int kt = 0; kt < T_; kt += 2 * BK) {
        __syncthreads();                       // buf0(kt) staged
        STAGE(1, kt + BK)                      // prefetch buf1
        COMPUTE(0)
        __syncthreads();                       // buf1 staged; buf0 reads done
        if (kt + 2 * BK < T_) STAGE(0, kt + 2 * BK)
        COMPUTE(1)
    }

    // Epilogue: D[row=(lane>>4)*4+r][col=lane&15] (m89/m91) + bias.
    float* outb = out + (size_t)b * N_ * O_ + (size_t)(tm * BM) * O_ + (tn * BN);
    const int cn = lane & 15;
    const int cr = (lane >> 4) * 4;
#pragma unroll
    for (int ni = 0; ni < 2; ++ni) {
        const int col = wn + ni * 16 + cn;
        const float bv = bias[tn * BN + col];
#pragma unroll
        for (int mi = 0; mi < 4; ++mi) {
#pragma unroll
            for (int r = 0; r < 4; ++r) {
                const int row = wm + mi * 16 + cr + r;
                outb[(size_t)row * O_ + col] = acc[mi][ni][r] + bv;
            }
        }
    }
}

// --- Fallback (ws too small): correct fp32 path.
__global__ __launch_bounds__(256) void naive_kernel(
    const float* __restrict__ x, const float* __restrict__ y,
    const float* __restrict__ w, const float* __restrict__ mask,
    const float* __restrict__ bias, float* __restrict__ out)
{
    const int oc = blockIdx.x & 3;
    const int n  = (blockIdx.x >> 2) & (N_ - 1);
    const int b  = blockIdx.x >> 10;

    __shared__ float xs[T_];
    __shared__ float ys[G_];
    const float* xrow = x + ((size_t)b * N_ + n) * T_;
    for (int i = threadIdx.x; i < T_ / 4; i += 256)
        ((float4*)xs)[i] = ((const float4*)xrow)[i];
    if (threadIdx.x < G_) ys[threadIdx.x] = y[b * G_ + threadIdx.x];
    __syncthreads();

    const int o = oc * 256 + threadIdx.x;
    float acc = 0.f;
    for (int t = 0; t < T_; t += 4) {
        const float4 m4 = *(const float4*)(mask + (size_t)o * T_ + t);
        float4 s = {0.f, 0.f, 0.f, 0.f};
#pragma unroll
        for (int g = 0; g < G_; ++g) {
            const float4 w4 = *(const float4*)(w + ((size_t)g * O_ + o) * T_ + t);
            const float yv = ys[g];
            s.x += yv * w4.x; s.y += yv * w4.y; s.z += yv * w4.z; s.w += yv * w4.w;
        }
        acc += xs[t] * m4.x * s.x + xs[t + 1] * m4.y * s.y
             + xs[t + 2] * m4.z * s.z + xs[t + 3] * m4.w * s.w;
    }
    out[((size_t)b * N_ + n) * O_ + o] = acc + bias[o];
}

extern "C" void kernel_launch(void* const* d_in, const int* in_sizes, int n_in,
                              void* d_out, int out_size, void* d_ws, size_t ws_size,
                              hipStream_t stream) {
    const float* x    = (const float*)d_in[0];
    const float* y    = (const float*)d_in[1];
    const float* w    = (const float*)d_in[2];
    const float* mask = (const float*)d_in[3];
    const float* bias = (const float*)d_in[4];
    float* out = (float*)d_out;

    const size_t wb_bytes = (size_t)B_ * WSTRIDE * sizeof(unsigned short); // 64 MiB + 128 KB
    const size_t xb_bytes = (size_t)B_ * N_ * T_ * sizeof(unsigned short); // 16 MiB

    if (ws_size >= wb_bytes + xb_bytes) {
        unsigned short* Wb = (unsigned short*)d_ws;
        unsigned short* xb = (unsigned short*)((char*)d_ws + wb_bytes);
        prep_kernel<<<MIXB + CVTB, 256, 0, stream>>>(w, mask, y, x, Wb, xb);
        dim3 grid(O_ / BN, N_ / BM, B_);
        gemm_kernel<<<grid, 512, 0, stream>>>(xb, Wb, bias, out);
    } else {
        naive_kernel<<<B_ * N_ * (O_ / 256), 256, 0, stream>>>(x, y, w, mask, bias, out);
    }
}

// Round 9
// 158.949 us; speedup vs baseline: 1.0209x; 1.0030x over previous
//
#include <hip/hip_runtime.h>
#include <hip/hip_bf16.h>
#include <stdint.h>

// out[b,n,o] = sum_t x[b,n,t] * (sum_g y[b,g]*w[g,o,t]*mask[o,t]) + bias[o]
// B=32 N=256 T=1024 O=1024 G=8.  bf16 MFMA path (absmax 0.031 vs thr 0.154).
//
//  K1 prep (R8 unchanged, plateau 43us): mix 1024 blocks (4t/thread, 32-b
//           staggered loop, w read once) + cvt 1024 blocks.  Wb b-stride padded.
//  K2 gemm (REWRITTEN): was LDS-read bound (16x16 MFMA: 2300 cyc ds_read vs
//           1000 cyc MFMA per CU per k-tile).  Now mfma_32x32x16, wave tile
//           64x64 (2x2), 4 waves/block, 128x128 tile, BK=64, dbuf, swizzle:
//           b128 reads/MAC -33%, MFMA instrs /4, epilogue 128B segments.

#define B_ 32
#define N_ 256
#define T_ 1024
#define O_ 1024
#define G_ 8

#define WSTRIDE ((size_t)(O_ * T_ + 2048))   // padded b-slice stride, elems

#define BM 128
#define BN 128
#define BK 64            // elems; LDS row = 128 B = 8 x 16 B chunks
#define BUFSZ (BM * BK)  // 8192 elems = 16 KiB

typedef __attribute__((__ext_vector_type__(8)))  __bf16 bf16x8;
typedef __attribute__((__ext_vector_type__(16))) float  f32x16;

__device__ __forceinline__ unsigned short f2bf(float f) {
    union { float f; uint32_t u; } v; v.f = f;
    uint32_t u = v.u;
    uint32_t r = (u + 0x7fffu + ((u >> 16) & 1u)) >> 16;  // RNE
    return (unsigned short)r;
}

__device__ __forceinline__ uint4 pack8(const float* a) {
    uint4 r;
    r.x = (uint32_t)f2bf(a[0]) | ((uint32_t)f2bf(a[1]) << 16);
    r.y = (uint32_t)f2bf(a[2]) | ((uint32_t)f2bf(a[3]) << 16);
    r.z = (uint32_t)f2bf(a[4]) | ((uint32_t)f2bf(a[5]) << 16);
    r.w = (uint32_t)f2bf(a[6]) | ((uint32_t)f2bf(a[7]) << 16);
    return r;
}

#define MIXB 1024   // O*T/4 threads / 256
#define CVTB 1024   // 262144 threads, 8 float4 each

// --- K1: fused prologue (R8 byte-identical).
__global__ __launch_bounds__(256) void prep_kernel(
    const float* __restrict__ w,     // [G,O,T]
    const float* __restrict__ mask,  // [O,T]
    const float* __restrict__ y,     // [B,G]
    const float* __restrict__ x,     // [B,N,T]
    unsigned short* __restrict__ Wb, // [B][WSTRIDE] bf16 (padded)
    unsigned short* __restrict__ xb) // [B,N,T] bf16
{
    const int tid = threadIdx.x;
    if (blockIdx.x < MIXB) {
        const int idx = blockIdx.x * 256 + tid;   // over O*T/4
        const int o   = idx >> 8;
        const int t   = (idx & 255) << 2;

        const float4 m4 = *(const float4*)(mask + (size_t)o * T_ + t);

        float wv[G_][4];
#pragma unroll
        for (int g = 0; g < G_; ++g) {
            const float4 a = *(const float4*)(w + ((size_t)g * O_ + o) * T_ + t);
            wv[g][0] = a.x * m4.x; wv[g][1] = a.y * m4.y;
            wv[g][2] = a.z * m4.z; wv[g][3] = a.w * m4.w;
        }
        unsigned short* dst = Wb + (size_t)o * T_ + t;
        const int bph = blockIdx.x & (B_ - 1);
#pragma unroll 4
        for (int bi = 0; bi < B_; ++bi) {
            const int b = (bi + bph) & (B_ - 1);
            const float4 y0 = *(const float4*)(y + b * G_);
            const float4 y1 = *(const float4*)(y + b * G_ + 4);
            const float yv[G_] = {y0.x, y0.y, y0.z, y0.w, y1.x, y1.y, y1.z, y1.w};
            float acc[4] = {};
#pragma unroll
            for (int g = 0; g < G_; ++g)
#pragma unroll
                for (int j = 0; j < 4; ++j)
                    acc[j] += yv[g] * wv[g][j];
            ushort4 pk;
            pk.x = f2bf(acc[0]); pk.y = f2bf(acc[1]);
            pk.z = f2bf(acc[2]); pk.w = f2bf(acc[3]);
            *(ushort4*)(dst + (size_t)b * WSTRIDE) = pk;
        }
    } else {
        const int i = (blockIdx.x - MIXB) * 256 + tid;
        const float4* x4 = (const float4*)x;
        uint4* o4 = (uint4*)xb;
#pragma unroll
        for (int j = 0; j < 4; ++j) {
            const size_t f4 = (size_t)j * 524288 + (size_t)i * 2;
            const float4 a = x4[f4];
            const float4 b = x4[f4 + 1];
            const float v[8] = {a.x, a.y, a.z, a.w, b.x, b.y, b.z, b.w};
            o4[(size_t)j * 262144 + i] = pack8(v);
        }
    }
}

__device__ __forceinline__ void load16_to_lds(const unsigned short* g, unsigned short* l) {
    __builtin_amdgcn_global_load_lds(
        (const __attribute__((address_space(1))) unsigned char*)g,
        (__attribute__((address_space(3))) unsigned char*)l,
        16, 0, 0);
}

// --- K2: batched GEMM, C = A . B^T, K-major bf16, mfma_32x32x16.
// 256 threads = 4 waves (2m x 2n), wave tile 64x64 = 2x2 of 32x32, acc 2x2xf32x16.
// A-frag: m=lane&31, k=(lane>>5)*8+j  (mirror of the verified 16x16 mapping);
// B-frag symmetric. C/D: col=lane&31, row=(reg&3)+8*(reg>>2)+4*(lane>>5) [m74/m101].
// LDS chunk c of row r holds global chunk (c ^ (r&7)) -> conflict-free b128.
__global__ __launch_bounds__(256, 2) void gemm_kernel(
    const unsigned short* __restrict__ xb,   // [B][N_][T_] bf16
    const unsigned short* __restrict__ Wb,   // [B][WSTRIDE] bf16 (padded)
    const float* __restrict__ bias,          // [O_]
    float* __restrict__ out)                 // [B][N_][O_] f32
{
    __shared__ __align__(16) unsigned short lA[2 * BUFSZ];  // 32 KiB
    __shared__ __align__(16) unsigned short lB[2 * BUFSZ];  // 32 KiB

    const int tn = blockIdx.x;   // 0..7  (o tiles)
    const int tm = blockIdx.y;   // 0..1  (n tiles)
    const int b  = blockIdx.z;   // 0..31

    const int tid  = threadIdx.x;
    const int lane = tid & 63;
    const int wave = tid >> 6;          // 0..3
    const int wm   = (wave >> 1) * 64;
    const int wn   = (wave & 1) * 64;

    const unsigned short* Ab = xb + (size_t)b * N_ * T_ + (size_t)(tm * BM) * T_;
    const unsigned short* Bb = Wb + (size_t)b * WSTRIDE + (size_t)(tn * BN) * T_;

    // staging (256 thr): round i: LDS elem tid*8 + i*2048 -> row tid/8 + i*32
    const int srow   = tid >> 3;                 // 0..31
    const int schunk = (tid & 7) ^ (srow & 7);   // (i*32)&7==0 -> round-invariant
    const unsigned short* ga0 = Ab + (size_t)srow * T_ + schunk * 8;
    const unsigned short* gb0 = Bb + (size_t)srow * T_ + schunk * 8;

#define STAGE(buf, kt)                                                          \
    {                                                                           \
        unsigned short* lad = lA + (buf) * BUFSZ + tid * 8;                     \
        unsigned short* lbd = lB + (buf) * BUFSZ + tid * 8;                     \
        _Pragma("unroll")                                                       \
        for (int i_ = 0; i_ < 4; ++i_) {                                        \
            load16_to_lds(ga0 + (kt) + (size_t)(i_ * 32) * T_, lad + i_ * 2048);\
            load16_to_lds(gb0 + (kt) + (size_t)(i_ * 32) * T_, lbd + i_ * 2048);\
        }                                                                       \
    }

    f32x16 acc[2][2] = {};

    const int fr   = lane & 31;      // fragment row within 32
    const int half = lane >> 5;      // k-half 0/1 (8 elems each)
    const int sw   = fr & 7;         // swizzle term (wm, mi*32 are multiples of 8)

#define COMPUTE(buf)                                                            \
    {                                                                           \
        const unsigned short* la = lA + (buf) * BUFSZ;                          \
        const unsigned short* lb = lB + (buf) * BUFSZ;                          \
        _Pragma("unroll")                                                       \
        for (int ks = 0; ks < 4; ++ks) {                                        \
            const int cp = (((ks * 2 + half)) ^ sw) * 8;                        \
            bf16x8 afr[2], bfr[2];                                              \
            _Pragma("unroll")                                                   \
            for (int i_ = 0; i_ < 2; ++i_)                                      \
                afr[i_] = *(const bf16x8*)(la + (wm + i_ * 32 + fr) * BK + cp); \
            _Pragma("unroll")                                                   \
            for (int i_ = 0; i_ < 2; ++i_)                                      \
                bfr[i_] = *(const bf16x8*)(lb + (wn + i_ * 32 + fr) * BK + cp); \
            _Pragma("unroll")                                                   \
            for (int mi = 0; mi < 2; ++mi)                                      \
                _Pragma("unroll")                                               \
                for (int ni = 0; ni < 2; ++ni)                                  \
                    acc[mi][ni] = __builtin_amdgcn_mfma_f32_32x32x16_bf16(      \
                        afr[mi], bfr[ni], acc[mi][ni], 0, 0, 0);                \
        }                                                                       \
    }

    STAGE(0, 0)
    for (int kt = 0; kt < T_; kt += 2 * BK) {
        __syncthreads();                       // buf0(kt) staged
        STAGE(1, kt + BK)                      // prefetch buf1
        COMPUTE(0)
        __syncthreads();                       // buf1 staged; buf0 reads done
        if (kt + 2 * BK < T_) STAGE(0, kt + 2 * BK)
        COMPUTE(1)
    }

    // Epilogue: D col=lane&31, row=(reg&3)+8*(reg>>2)+4*(lane>>5)  + bias.
    float* outb = out + (size_t)b * N_ * O_ + (size_t)(tm * BM) * O_ + (tn * BN);
    const int cn = lane & 31;
    const int rb = (lane >> 5) * 4;
#pragma unroll
    for (int ni = 0; ni < 2; ++ni) {
        const int col = wn + ni * 32 + cn;
        const float bv = bias[tn * BN + col];
#pragma unroll
        for (int mi = 0; mi < 2; ++mi) {
#pragma unroll
            for (int r = 0; r < 16; ++r) {
                const int row = wm + mi * 32 + rb + (r & 3) + 8 * (r >> 2);
                outb[(size_t)row * O_ + col] = acc[mi][ni][r] + bv;
            }
        }
    }
}

// --- Fallback (ws too small): correct fp32 path.
__global__ __launch_bounds__(256) void naive_kernel(
    const float* __restrict__ x, const float* __restrict__ y,
    const float* __restrict__ w, const float* __restrict__ mask,
    const float* __restrict__ bias, float* __restrict__ out)
{
    const int oc = blockIdx.x & 3;
    const int n  = (blockIdx.x >> 2) & (N_ - 1);
    const int b  = blockIdx.x >> 10;

    __shared__ float xs[T_];
    __shared__ float ys[G_];
    const float* xrow = x + ((size_t)b * N_ + n) * T_;
    for (int i = threadIdx.x; i < T_ / 4; i += 256)
        ((float4*)xs)[i] = ((const float4*)xrow)[i];
    if (threadIdx.x < G_) ys[threadIdx.x] = y[b * G_ + threadIdx.x];
    __syncthreads();

    const int o = oc * 256 + threadIdx.x;
    float acc = 0.f;
    for (int t = 0; t < T_; t += 4) {
        const float4 m4 = *(const float4*)(mask + (size_t)o * T_ + t);
        float4 s = {0.f, 0.f, 0.f, 0.f};
#pragma unroll
        for (int g = 0; g < G_; ++g) {
            const float4 w4 = *(const float4*)(w + ((size_t)g * O_ + o) * T_ + t);
            const float yv = ys[g];
            s.x += yv * w4.x; s.y += yv * w4.y; s.z += yv * w4.z; s.w += yv * w4.w;
        }
        acc += xs[t] * m4.x * s.x + xs[t + 1] * m4.y * s.y
             + xs[t + 2] * m4.z * s.z + xs[t + 3] * m4.w * s.w;
    }
    out[((size_t)b * N_ + n) * O_ + o] = acc + bias[o];
}

extern "C" void kernel_launch(void* const* d_in, const int* in_sizes, int n_in,
                              void* d_out, int out_size, void* d_ws, size_t ws_size,
                              hipStream_t stream) {
    const float* x    = (const float*)d_in[0];
    const float* y    = (const float*)d_in[1];
    const float* w    = (const float*)d_in[2];
    const float* mask = (const float*)d_in[3];
    const float* bias = (const float*)d_in[4];
    float* out = (float*)d_out;

    const size_t wb_bytes = (size_t)B_ * WSTRIDE * sizeof(unsigned short); // 64 MiB + 128 KB
    const size_t xb_bytes = (size_t)B_ * N_ * T_ * sizeof(unsigned short); // 16 MiB

    if (ws_size >= wb_bytes + xb_bytes) {
        unsigned short* Wb = (unsigned short*)d_ws;
        unsigned short* xb = (unsigned short*)((char*)d_ws + wb_bytes);
        prep_kernel<<<MIXB + CVTB, 256, 0, stream>>>(w, mask, y, x, Wb, xb);
        dim3 grid(O_ / BN, N_ / BM, B_);
        gemm_kernel<<<grid, 256, 0, stream>>>(xb, Wb, bias, out);
    } else {
        naive_kernel<<<B_ * N_ * (O_ / 256), 256, 0, stream>>>(x, y, w, mask, bias, out);
    }
}